// Round 12
// baseline (28.886 us; speedup 1.0000x reference)
//
#include <hip/hip_runtime.h>

#define NPART 62
#define M     256
#define DD    256
#define NPOS  8
#define NNEG  248
#define MARG  0.2f
#define REC   512

#define WS_NEED ((size_t)(496 * REC) * 4)

#define OFF_HARD 15376
#define OFF_MD   15438
#define OFF_FN   15439

typedef _Float16 f16x8 __attribute__((ext_vector_type(8)));
typedef float    f32x4 __attribute__((ext_vector_type(4)));

#define PITCH 258

// fragment-slot swizzle (both sides): position of (row&15, k-octet g) in a 64-slot slab.
__device__ __forceinline__ int fragpos(int r15, int g) { return (r15 ^ (g << 1)) + (g << 4); }

// convert 16 fp32 -> 2 octets of hi/lo f16 fragments + return sum of squares
__device__ __forceinline__ float cvtstore(_Float16* SW, const int whalf[2][2],
                                          float4 a, float4 b, float4 c, float4 d)
{
    float x2 = 0.f;
    float xx[16] = {a.x, a.y, a.z, a.w, b.x, b.y, b.z, b.w,
                    c.x, c.y, c.z, c.w, d.x, d.y, d.z, d.w};
#pragma unroll
    for (int u = 0; u < 2; ++u) {
        f16x8 hv, lv;
#pragma unroll
        for (int j = 0; j < 8; ++j) {
            float x = xx[u * 8 + j];
            x2 += x * x;
            _Float16 h = (_Float16)x;
            hv[j] = h;
            lv[j] = (_Float16)(x - (float)h);
        }
        *(f16x8*)(SW + whalf[u][0]) = hv;
        *(f16x8*)(SW + whalf[u][1]) = lv;
    }
    return x2;
}

// ======================= fused convert + staged MFMA dist + mining =======================
// 496 blocks (8 XCD x 62), 512 threads. Block = (part p, 32-row tile t32). 2 blocks/CU.
__global__ __launch_bounds__(512, 4) void k_all(const float* __restrict__ F,
                                                const int* __restrict__ label,
                                                float* __restrict__ recs)
{
    // 2 x 32KB double-buffered fragment stage; after GEMM overlaid by:
    //   dist[32][PITCH] @0 (33,024B) | fullS[8][248] @33,024 | fullC[8][248] @40,960
    __shared__ __align__(16) char smem[65536];
    __shared__ float x2s[M];
    __shared__ float posbuf[8][NPOS];
    __shared__ float wred[16];

    const int bxr = blockIdx.x;                       // 496 = 8 XCD * 62
    const int swz = (bxr & 7) * 62 + (bxr >> 3);      // bijective; part's 8 blocks same-XCD
    const int p   = swz >> 3;
    const int t32 = swz & 7;
    const int ib  = t32 * 32;                         // anchor base (global row)
    const int a0  = t32 * 2;                          // first A row-tile (of 16)
    const int t   = threadIdx.x;
    const int lane = t & 63;
    const int w    = t >> 6;                          // wave 0..7

    const float* Fp = F + (size_t)p * (M * DD);

    // staging role: thread t covers (row = t>>1, octets 2sp..2sp+1) of each 32-k slab
    const int srow  = t >> 1;
    const int sp    = t & 1;
    const int stile = srow >> 4;
    int whalf[2][2];
#pragma unroll
    for (int u = 0; u < 2; ++u) {
        int o   = 2 * sp + u;
        int pos = fragpos(srow & 15, o);
        whalf[u][0] = ((stile * 2 + 0) * 64 + pos) * 8;
        whalf[u][1] = ((stile * 2 + 1) * 64 + pos) * 8;
    }
    const float* gsrc = Fp + srow * DD + sp * 16;
    const int flane = fragpos(lane & 15, lane >> 4);  // compute-side fragment lane

    _Float16* stage0 = (_Float16*)smem;
    _Float16* stage1 = (_Float16*)(smem + 32768);

    f32x4 acc[2][2];
#pragma unroll
    for (int rt = 0; rt < 2; ++rt)
#pragma unroll
        for (int c = 0; c < 2; ++c) acc[rt][c] = (f32x4){0.f, 0.f, 0.f, 0.f};
    float x2p = 0.f;

    // prologue: slab 0 -> stage0
    {
        float4 c0 = *(const float4*)(gsrc + 0);
        float4 c1 = *(const float4*)(gsrc + 4);
        float4 c2 = *(const float4*)(gsrc + 8);
        float4 c3 = *(const float4*)(gsrc + 12);
        x2p += cvtstore(stage0, whalf, c0, c1, c2, c3);
    }
    __syncthreads();

#pragma unroll
    for (int s = 0; s < 8; ++s) {
        float4 n0, n1, n2, n3;
        if (s < 7) {                                   // issue next-slab loads early (T14)
            const float* g = gsrc + (s + 1) * 32;
            n0 = *(const float4*)(g + 0);
            n1 = *(const float4*)(g + 4);
            n2 = *(const float4*)(g + 8);
            n3 = *(const float4*)(g + 12);
        }
        // compute slab s: wave w -> col-tiles {2w, 2w+1} x row-tiles {a0, a0+1}
        const _Float16* SB = (s & 1) ? stage1 : stage0;
        {
            f16x8 Bh[2], Bl[2], Ah[2], Al[2];
#pragma unroll
            for (int c = 0; c < 2; ++c) {
                int ct = 2 * w + c;
                Bh[c] = *(const f16x8*)(SB + ((ct * 2 + 0) * 64 + flane) * 8);
                Bl[c] = *(const f16x8*)(SB + ((ct * 2 + 1) * 64 + flane) * 8);
            }
#pragma unroll
            for (int rt = 0; rt < 2; ++rt) {
                Ah[rt] = *(const f16x8*)(SB + (((a0 + rt) * 2 + 0) * 64 + flane) * 8);
                Al[rt] = *(const f16x8*)(SB + (((a0 + rt) * 2 + 1) * 64 + flane) * 8);
            }
#pragma unroll
            for (int rt = 0; rt < 2; ++rt)
#pragma unroll
                for (int c = 0; c < 2; ++c) {
                    acc[rt][c] = __builtin_amdgcn_mfma_f32_16x16x32_f16(Ah[rt], Bh[c], acc[rt][c], 0, 0, 0);
                    acc[rt][c] = __builtin_amdgcn_mfma_f32_16x16x32_f16(Ah[rt], Bl[c], acc[rt][c], 0, 0, 0);
                    acc[rt][c] = __builtin_amdgcn_mfma_f32_16x16x32_f16(Al[rt], Bh[c], acc[rt][c], 0, 0, 0);
                }
        }
        if (s < 7) {                                   // convert + write slab s+1 (other buffer)
            _Float16* SW = (s & 1) ? stage0 : stage1;
            x2p += cvtstore(SW, whalf, n0, n1, n2, n3);
            __syncthreads();                           // writes visible before next compute
        }
    }

    // ---- x2: pair-reduce (t with t^1 shares a row), publish ----
    x2p += __shfl_xor(x2p, 1);
    if (sp == 0) x2s[srow] = x2p;
    __syncthreads();   // x2s ready AND all waves done with stage buffers

    // ---- epilogue: dist -> region (overlays stage0) ----
    float* region = (float*)smem;
    const int cbase = lane & 15;
    const int rbase = (lane >> 4) * 4;
#pragma unroll
    for (int rt = 0; rt < 2; ++rt)
#pragma unroll
        for (int c = 0; c < 2; ++c) {
            const float xj = x2s[(2 * w + c) * 16 + cbase];
#pragma unroll
            for (int r = 0; r < 4; ++r) {
                int lrow = rt * 16 + rbase + r;
                float xi = x2s[ib + lrow];
                float d2 = xi + xj - 2.f * acc[rt][c][r];
                region[lrow * PITCH + (2 * w + c) * 16 + cbase] = sqrtf(fmaxf(d2, 0.f) + 1e-12f);
            }
        }
    __syncthreads();

    // ---- mining: wave-private (wave w owns local anchors w*4..w*4+3) ----
    float* fullS = (float*)(smem + 33024);             // overlays stage1 tail
    float* fullC = (float*)(smem + 33024 + 7936);

    int llab[4];
#pragma unroll
    for (int ch = 0; ch < 4; ++ch) llab[ch] = label[p * M + ch * 64 + lane];

    for (int idx = lane; idx < NNEG; idx += 64) {
        fullS[w * NNEG + idx] = 0.f;
        fullC[w * NNEG + idx] = 0.f;
    }

    const unsigned long long lmask = (1ull << lane) - 1ull;
    float hardAcc = 0.f, rowSum = 0.f;

    for (int a = 0; a < 4; ++a) {
        const int ii = w * 4 + a;
        const int li = label[p * M + ib + ii];         // wave-uniform
        int runMatch = 0;
        float negmin = 3.4e38f;
        float ndv[4]; int nqv[4]; int nval[4];
#pragma unroll
        for (int ch = 0; ch < 4; ++ch) {
            const int j = ch * 64 + lane;
            float d = region[ii * PITCH + j];
            bool match = (llab[ch] == li);
            unsigned long long bal = __ballot(match);
            int posRank = runMatch + __popcll(bal & lmask);
            if (match) {
                if (posRank < NPOS) posbuf[w][posRank] = d;
                nval[ch] = 0; ndv[ch] = 0.f; nqv[ch] = 0;
            } else {
                ndv[ch] = d; nqv[ch] = j - posRank; nval[ch] = 1;
                negmin = fminf(negmin, d);
            }
            runMatch += __popcll(bal);
            rowSum += d;
        }
        asm volatile("s_waitcnt lgkmcnt(0)" ::: "memory");  // same-wave posbuf drain

        float maxpos = posbuf[w][0];
#pragma unroll
        for (int pp = 1; pp < NPOS; ++pp) maxpos = fmaxf(maxpos, posbuf[w][pp]);
#pragma unroll
        for (int off = 32; off >= 1; off >>= 1)
            negmin = fminf(negmin, __shfl_xor(negmin, off));
        hardAcc += fmaxf(MARG + maxpos - negmin, 0.f);

#pragma unroll
        for (int ch = 0; ch < 4; ++ch) {
            if (nval[ch]) {
                float dneg = ndv[ch]; int q = nqv[ch];
                float s = 0.f, cnt = 0.f;
#pragma unroll
                for (int pp = 0; pp < NPOS; ++pp) {
                    float v = MARG + posbuf[w][pp] - dneg;
                    if (v > 0.f) { s += v; cnt += 1.f; }
                }
                fullS[w * NNEG + q] += s;              // per-wave private; q distinct per lane
                fullC[w * NNEG + q] += cnt;
            }
        }
    }

#pragma unroll
    for (int off = 32; off >= 1; off >>= 1) rowSum += __shfl_xor(rowSum, off);
    if (lane == 0) { wred[w] = hardAcc; wred[8 + w] = rowSum; }
    __syncthreads();

    float* rec = recs + (size_t)swz * REC;
    if (t < NNEG) {
        float s = 0.f, c = 0.f;
#pragma unroll
        for (int v = 0; v < 8; ++v) { s += fullS[v * NNEG + t]; c += fullC[v * NNEG + t]; }
        rec[t] = s;
        rec[NNEG + t] = c;
    }
    if (t == 0) {
        float h = 0.f, ds = 0.f;
#pragma unroll
        for (int v = 0; v < 8; ++v) { h += wred[v]; ds += wred[8 + v]; }
        rec[496] = h;
        rec[497] = ds;
    }
}

// ======================= merged finalize: 63 blocks, 8 recs/part =======================
__global__ __launch_bounds__(256) void k_fin(const float* __restrict__ recs,
                                             float* __restrict__ out)
{
    const int p = blockIdx.x;
    const int t = threadIdx.x;
    if (p < NPART) {
        if (t < NNEG) {
            float s = 0.f, c = 0.f;
#pragma unroll
            for (int a = 0; a < 8; ++a) {
                const float* rec = recs + (size_t)(p * 8 + a) * REC;
                s += rec[t];
                c += rec[NNEG + t];
            }
            out[p * NNEG + t]          = s / (c + 1e-6f);
            out[OFF_FN + p * NNEG + t] = c;
        }
        if (t == 0) {
            float h = 0.f;
#pragma unroll
            for (int a = 0; a < 8; ++a) h += recs[(size_t)(p * 8 + a) * REC + 496];
            out[OFF_HARD + p] = h * (1.0f / 256.0f);
        }
    } else {
        __shared__ float red[4];
        float v = 0.f;
        for (int i = t; i < 496; i += 256) v += recs[(size_t)i * REC + 497];
#pragma unroll
        for (int off = 32; off >= 1; off >>= 1) v += __shfl_xor(v, off);
        if ((t & 63) == 0) red[t >> 6] = v;
        __syncthreads();
        if (t == 0)
            out[OFF_MD] = (red[0] + red[1] + red[2] + red[3]) / (float)((size_t)NPART * M * M);
    }
}

// ======================= fallback: proven round-1 fused path =======================
__global__ __launch_bounds__(256) void fb_main(
    const float* __restrict__ F, const int* __restrict__ label, float* __restrict__ ws)
{
    __shared__ __align__(16) float region[256 * 36];
    __shared__ float x2s[M];
    __shared__ int   lab[M];
    __shared__ float posbuf[4][NPOS];
    __shared__ float fullS[4][NNEG];
    __shared__ float fullC[4][NNEG];
    __shared__ float wred[8];

    const int bx = blockIdx.x;
    const int p  = bx >> 3;
    const int ib = (bx & 7) * 32;
    const int t  = threadIdx.x;

    lab[t] = label[p * M + t];
    for (int idx = t; idx < 4 * NNEG; idx += 256) {
        (&fullS[0][0])[idx] = 0.f;
        (&fullC[0][0])[idx] = 0.f;
    }
    __syncthreads();

    const float4* Fv = (const float4*)(F + (size_t)p * (M * DD));

    float acc[4][8];
#pragma unroll
    for (int r = 0; r < 4; ++r)
#pragma unroll
        for (int c = 0; c < 8; ++c) acc[r][c] = 0.f;

    float x2loc = 0.f;
    const int tc = t & 31;
    const int tg = t >> 5;

    for (int kt = 0; kt < 8; ++kt) {
#pragma unroll
        for (int w = 0; w < 8; ++w) {
            int ch = w * 256 + t;
            int r  = ch >> 3;
            int q  = ch & 7;
            float4 v = Fv[r * 64 + kt * 8 + q];
            float* dst = &region[r * 36 + q * 4];
            dst[0] = v.x; dst[1] = v.y; dst[2] = v.z; dst[3] = v.w;
        }
        __syncthreads();
#pragma unroll
        for (int k4 = 0; k4 < 8; ++k4) {
            float4 b = *(const float4*)&region[t * 36 + k4 * 4];
            x2loc += b.x * b.x + b.y * b.y + b.z * b.z + b.w * b.w;
        }
#pragma unroll
        for (int k4 = 0; k4 < 8; ++k4) {
            float4 a4[4], b4[8];
#pragma unroll
            for (int r = 0; r < 4; ++r)
                a4[r] = *(const float4*)&region[(ib + tg * 4 + r) * 36 + k4 * 4];
#pragma unroll
            for (int c = 0; c < 8; ++c)
                b4[c] = *(const float4*)&region[(tc + 32 * c) * 36 + k4 * 4];
#pragma unroll
            for (int r = 0; r < 4; ++r)
#pragma unroll
                for (int c = 0; c < 8; ++c)
                    acc[r][c] += a4[r].x * b4[c].x + a4[r].y * b4[c].y +
                                 a4[r].z * b4[c].z + a4[r].w * b4[c].w;
        }
        __syncthreads();
    }

    x2s[t] = x2loc;
    __syncthreads();

#pragma unroll
    for (int r = 0; r < 4; ++r) {
        int ii = tg * 4 + r;
        float xi = x2s[ib + ii];
#pragma unroll
        for (int c = 0; c < 8; ++c) {
            int j = tc + 32 * c;
            float d2 = xi + x2s[j] - 2.f * acc[r][c];
            region[ii * M + j] = sqrtf(fmaxf(d2, 0.f) + 1e-12f);
        }
    }
    __syncthreads();

    const int lane = t & 63;
    const int w    = t >> 6;
    const unsigned long long lmask = (1ull << lane) - 1ull;

    float hardAcc = 0.f;
    float rowSum  = 0.f;

    for (int a = 0; a < 8; ++a) {
        int ii = w * 8 + a;
        int li = lab[ib + ii];
        int runMatch = 0;
        float negmin = 3.4e38f;
        float ndv[4]; int nqv[4]; int nval[4];
#pragma unroll
        for (int ch = 0; ch < 4; ++ch) {
            int j = ch * 64 + lane;
            float d = region[ii * M + j];
            bool match = (lab[j] == li);
            unsigned long long bal = __ballot(match);
            int prefix  = __popcll(bal & lmask);
            int posRank = runMatch + prefix;
            if (match) {
                if (posRank < NPOS) posbuf[w][posRank] = d;
                nval[ch] = 0; ndv[ch] = 0.f; nqv[ch] = 0;
            } else {
                ndv[ch] = d; nqv[ch] = j - posRank; nval[ch] = 1;
                negmin = fminf(negmin, d);
            }
            runMatch += __popcll(bal);
            rowSum += d;
        }
        __syncthreads();

        float maxpos = posbuf[w][0];
#pragma unroll
        for (int pp = 1; pp < NPOS; ++pp) maxpos = fmaxf(maxpos, posbuf[w][pp]);
#pragma unroll
        for (int off = 32; off >= 1; off >>= 1)
            negmin = fminf(negmin, __shfl_xor(negmin, off));
        hardAcc += fmaxf(MARG + maxpos - negmin, 0.f);

#pragma unroll
        for (int ch = 0; ch < 4; ++ch) {
            if (nval[ch]) {
                float dneg = ndv[ch]; int q = nqv[ch];
                float s = 0.f, cnt = 0.f;
#pragma unroll
                for (int pp = 0; pp < NPOS; ++pp) {
                    float v = MARG + posbuf[w][pp] - dneg;
                    if (v > 0.f) { s += v; cnt += 1.f; }
                }
                fullS[w][q] += s;
                fullC[w][q] += cnt;
            }
        }
        __syncthreads();
    }

#pragma unroll
    for (int off = 32; off >= 1; off >>= 1) rowSum += __shfl_xor(rowSum, off);
    if (lane == 0) { wred[w] = hardAcc; wred[4 + w] = rowSum; }
    __syncthreads();

    float* rec = ws + (size_t)bx * REC;
    if (t < NNEG) {
        float s = fullS[0][t] + fullS[1][t] + fullS[2][t] + fullS[3][t];
        float c = fullC[0][t] + fullC[1][t] + fullC[2][t] + fullC[3][t];
        rec[t] = s;
        rec[NNEG + t] = c;
    }
    if (t == 0) {
        rec[496] = wred[0] + wred[1] + wred[2] + wred[3];
        rec[497] = wred[4] + wred[5] + wred[6] + wred[7];
    }
}

// ======================= launch =======================
extern "C" void kernel_launch(void* const* d_in, const int* in_sizes, int n_in,
                              void* d_out, int out_size, void* d_ws, size_t ws_size,
                              hipStream_t stream)
{
    const float* F     = (const float*)d_in[0];
    const int*   label = (const int*)d_in[1];
    float*       ws    = (float*)d_ws;
    float*       out   = (float*)d_out;

    if (ws_size >= WS_NEED) {
        k_all<<<dim3(496), dim3(512), 0, stream>>>(F, label, ws);
        k_fin<<<dim3(63),  dim3(256), 0, stream>>>(ws, out);
    } else {
        fb_main<<<dim3(496), dim3(256), 0, stream>>>(F, label, ws);
        k_fin <<<dim3(63),  dim3(256), 0, stream>>>(ws, out);
    }
}

// Round 13
// 23.531 us; speedup vs baseline: 1.2276x; 1.2276x over previous
//
#include <hip/hip_runtime.h>

#define NPART 62
#define M     256
#define DD    256
#define NPOS  8
#define NNEG  248
#define MARG  0.2f
#define REC   512

#define WS_NEED ((size_t)(496 * REC) * 4)

#define OFF_HARD 15376
#define OFF_MD   15438
#define OFF_FN   15439

typedef _Float16 f16x8 __attribute__((ext_vector_type(8)));
typedef float    f32x4 __attribute__((ext_vector_type(4)));

#define PITCH 258

// fragment-slot swizzle (both sides): position of (row&15, k-octet g) in a 64-slot tile.
__device__ __forceinline__ int fragpos(int r15, int g) { return (r15 ^ (g << 1)) + (g << 4); }

// ======================= fused convert + staged MFMA dist + mining =======================
// 248 blocks (8 XCD x 31), 1024 threads. Block = (part p, 64-row tile rt4).
// Pure-f16 fragments (no hi/lo split): dist err ~4e-4, count-flip budget ~8 << 34.4.
__global__ __launch_bounds__(1024) void k_all(const float* __restrict__ F,
                                              const int* __restrict__ label,
                                              float* __restrict__ recs)
{
    // stage: 2 x 16KB f16 fragment slabs (dbuf); later overlaid by dist[64][PITCH] (66,048B)
    __shared__ __align__(16) char smem[64 * PITCH * 4];
    __shared__ float x2s[M];
    __shared__ float fullS[16][NNEG];
    __shared__ float fullC[16][NNEG];
    __shared__ float posbuf[16][NPOS];
    __shared__ float wred[32];

    const int bxr = blockIdx.x;                       // 248 = 8 XCD * 31
    const int swz = (bxr & 7) * 31 + (bxr >> 3);      // bijective; part's 4 tiles same-XCD
    const int p   = swz >> 2;
    const int rt4 = swz & 3;
    const int ib  = rt4 * 64;                         // anchor base (global row)
    const int a0  = rt4 * 4;                          // first A row-tile (of 16)
    const int t   = threadIdx.x;
    const int lane = t & 63;
    const int w    = t >> 6;                          // wave 0..15 = B col-tile

    const float* Fp = F + (size_t)p * (M * DD);

    // staging role: thread t covers (row = t>>2, k-octet = t&3) of each 32-k slab
    const int srow = t >> 2;
    const int soct = t & 3;
    const int stile = srow >> 4;
    const int whalf = ((stile * 64) + fragpos(srow & 15, soct)) * 8;
    const float* gsrc = Fp + srow * DD + soct * 8;

    // compute-side fragment lane position (swizzled, same involution as write side)
    const int flane = fragpos(lane & 15, lane >> 4);

    _Float16* stage0 = (_Float16*)smem;
    _Float16* stage1 = (_Float16*)(smem + 16384);

    f32x4 acc[4];
#pragma unroll
    for (int rt = 0; rt < 4; ++rt) acc[rt] = (f32x4){0.f, 0.f, 0.f, 0.f};

    float x2p = 0.f;
    float4 v0, v1, n0, n1;

    auto CVT = [&](_Float16* SW, float4 a, float4 b) {
        float xx[8] = {a.x, a.y, a.z, a.w, b.x, b.y, b.z, b.w};
        f16x8 hv;
#pragma unroll
        for (int j = 0; j < 8; ++j) {
            x2p += xx[j] * xx[j];
            hv[j] = (_Float16)xx[j];
        }
        *(f16x8*)(SW + whalf) = hv;
    };

    // prologue: slab 0 -> stage0
    v0 = *(const float4*)(gsrc + 0);
    v1 = *(const float4*)(gsrc + 4);
    CVT(stage0, v0, v1);
    __syncthreads();

#pragma unroll
    for (int s = 0; s < 8; ++s) {
        if (s < 7) {                                   // issue next-slab loads early (T14)
            n0 = *(const float4*)(gsrc + (s + 1) * 32 + 0);
            n1 = *(const float4*)(gsrc + (s + 1) * 32 + 4);
        }
        // compute slab s from stage[s&1]
        const _Float16* SB = (s & 1) ? stage1 : stage0;
        {
            f16x8 B = *(const f16x8*)(SB + (w * 64 + flane) * 8);
#pragma unroll
            for (int rt = 0; rt < 4; ++rt) {
                f16x8 A = *(const f16x8*)(SB + ((a0 + rt) * 64 + flane) * 8);
                acc[rt] = __builtin_amdgcn_mfma_f32_16x16x32_f16(A, B, acc[rt], 0, 0, 0);
            }
        }
        if (s < 7) {                                   // convert + write slab s+1 (other buffer)
            CVT((s & 1) ? stage0 : stage1, n0, n1);
            __syncthreads();                           // writes visible before next compute
        }
    }

    // ---- x2 (exact fp32): reduce over the 4 octets, publish ----
    x2p += __shfl_xor(x2p, 1);
    x2p += __shfl_xor(x2p, 2);
    if ((lane & 3) == 0) x2s[srow] = x2p;
    __syncthreads();   // x2s ready AND all waves done with stage buffers

    // ---- epilogue: dist -> LDS region (overlays stage) ----
    float* region = (float*)smem;
    const int cbase = lane & 15;
    const int rbase = (lane >> 4) * 4;
    const float xj = x2s[w * 16 + cbase];
#pragma unroll
    for (int rt = 0; rt < 4; ++rt)
#pragma unroll
        for (int r = 0; r < 4; ++r) {
            float xi = x2s[ib + rt * 16 + rbase + r];
            float d2 = xi + xj - 2.f * acc[rt][r];
            float dd = sqrtf(fmaxf(d2, 0.f) + 1e-12f);
            region[(rt * 16 + rbase + r) * PITCH + w * 16 + cbase] = dd;
        }
    __syncthreads();

    // ---- mining: wave-private (wave w owns local anchors w*4..w*4+3) ----
    int llab[4];
#pragma unroll
    for (int ch = 0; ch < 4; ++ch) llab[ch] = label[p * M + ch * 64 + lane];

    for (int idx = lane; idx < NNEG; idx += 64) { fullS[w][idx] = 0.f; fullC[w][idx] = 0.f; }

    const unsigned long long lmask = (1ull << lane) - 1ull;
    float hardAcc = 0.f, rowSum = 0.f;

    for (int a = 0; a < 4; ++a) {
        const int ii = w * 4 + a;
        const int li = label[p * M + ib + ii];   // wave-uniform
        int runMatch = 0;
        float negmin = 3.4e38f;
        float ndv[4]; int nqv[4]; int nval[4];
#pragma unroll
        for (int ch = 0; ch < 4; ++ch) {
            const int j = ch * 64 + lane;
            float d = region[ii * PITCH + j];
            bool match = (llab[ch] == li);
            unsigned long long bal = __ballot(match);
            int posRank = runMatch + __popcll(bal & lmask);
            if (match) {
                if (posRank < NPOS) posbuf[w][posRank] = d;
                nval[ch] = 0; ndv[ch] = 0.f; nqv[ch] = 0;
            } else {
                ndv[ch] = d; nqv[ch] = j - posRank; nval[ch] = 1;
                negmin = fminf(negmin, d);
            }
            runMatch += __popcll(bal);
            rowSum += d;
        }
        asm volatile("s_waitcnt lgkmcnt(0)" ::: "memory");  // same-wave posbuf drain

        float maxpos = posbuf[w][0];
#pragma unroll
        for (int pp = 1; pp < NPOS; ++pp) maxpos = fmaxf(maxpos, posbuf[w][pp]);
#pragma unroll
        for (int off = 32; off >= 1; off >>= 1)
            negmin = fminf(negmin, __shfl_xor(negmin, off));
        hardAcc += fmaxf(MARG + maxpos - negmin, 0.f);

#pragma unroll
        for (int ch = 0; ch < 4; ++ch) {
            if (nval[ch]) {
                float dneg = ndv[ch]; int q = nqv[ch];
                float s = 0.f, cnt = 0.f;
#pragma unroll
                for (int pp = 0; pp < NPOS; ++pp) {
                    float v = MARG + posbuf[w][pp] - dneg;
                    if (v > 0.f) { s += v; cnt += 1.f; }
                }
                fullS[w][q] += s;   // per-wave private; q distinct per lane
                fullC[w][q] += cnt;
            }
        }
    }

#pragma unroll
    for (int off = 32; off >= 1; off >>= 1) rowSum += __shfl_xor(rowSum, off);
    if (lane == 0) { wred[w] = hardAcc; wred[16 + w] = rowSum; }
    __syncthreads();

    float* rec = recs + (size_t)swz * REC;
    if (t < NNEG) {
        float s = 0.f, c = 0.f;
#pragma unroll
        for (int v = 0; v < 16; ++v) { s += fullS[v][t]; c += fullC[v][t]; }
        rec[t] = s;
        rec[NNEG + t] = c;
    }
    if (t == 0) {
        float h = 0.f, ds = 0.f;
#pragma unroll
        for (int v = 0; v < 16; ++v) { h += wred[v]; ds += wred[16 + v]; }
        rec[496] = h;
        rec[497] = ds;
    }
}

// ======================= merged finalize: 63 blocks, 4 recs/part =======================
__global__ __launch_bounds__(256) void k_fin(const float* __restrict__ recs,
                                             float* __restrict__ out)
{
    const int p = blockIdx.x;
    const int t = threadIdx.x;
    if (p < NPART) {
        if (t < NNEG) {
            float s = 0.f, c = 0.f;
#pragma unroll
            for (int a = 0; a < 4; ++a) {
                const float* rec = recs + (size_t)(p * 4 + a) * REC;
                s += rec[t];
                c += rec[NNEG + t];
            }
            out[p * NNEG + t]          = s / (c + 1e-6f);
            out[OFF_FN + p * NNEG + t] = c;
        }
        if (t == 0) {
            float h = 0.f;
#pragma unroll
            for (int a = 0; a < 4; ++a) h += recs[(size_t)(p * 4 + a) * REC + 496];
            out[OFF_HARD + p] = h * (1.0f / 256.0f);
        }
    } else {
        __shared__ float red[4];
        float v = (t < 248) ? recs[(size_t)t * REC + 497] : 0.f;
#pragma unroll
        for (int off = 32; off >= 1; off >>= 1) v += __shfl_xor(v, off);
        if ((t & 63) == 0) red[t >> 6] = v;
        __syncthreads();
        if (t == 0)
            out[OFF_MD] = (red[0] + red[1] + red[2] + red[3]) / (float)((size_t)NPART * M * M);
    }
}

// ======================= fallback: proven round-1 fused path =======================
__global__ __launch_bounds__(256) void fb_main(
    const float* __restrict__ F, const int* __restrict__ label, float* __restrict__ ws)
{
    __shared__ __align__(16) float region[256 * 36];
    __shared__ float x2s[M];
    __shared__ int   lab[M];
    __shared__ float posbuf[4][NPOS];
    __shared__ float fullS[4][NNEG];
    __shared__ float fullC[4][NNEG];
    __shared__ float wred[8];

    const int bx = blockIdx.x;
    const int p  = bx >> 3;
    const int ib = (bx & 7) * 32;
    const int t  = threadIdx.x;

    lab[t] = label[p * M + t];
    for (int idx = t; idx < 4 * NNEG; idx += 256) {
        (&fullS[0][0])[idx] = 0.f;
        (&fullC[0][0])[idx] = 0.f;
    }
    __syncthreads();

    const float4* Fv = (const float4*)(F + (size_t)p * (M * DD));

    float acc[4][8];
#pragma unroll
    for (int r = 0; r < 4; ++r)
#pragma unroll
        for (int c = 0; c < 8; ++c) acc[r][c] = 0.f;

    float x2loc = 0.f;
    const int tc = t & 31;
    const int tg = t >> 5;

    for (int kt = 0; kt < 8; ++kt) {
#pragma unroll
        for (int w = 0; w < 8; ++w) {
            int ch = w * 256 + t;
            int r  = ch >> 3;
            int q  = ch & 7;
            float4 v = Fv[r * 64 + kt * 8 + q];
            float* dst = &region[r * 36 + q * 4];
            dst[0] = v.x; dst[1] = v.y; dst[2] = v.z; dst[3] = v.w;
        }
        __syncthreads();
#pragma unroll
        for (int k4 = 0; k4 < 8; ++k4) {
            float4 b = *(const float4*)&region[t * 36 + k4 * 4];
            x2loc += b.x * b.x + b.y * b.y + b.z * b.z + b.w * b.w;
        }
#pragma unroll
        for (int k4 = 0; k4 < 8; ++k4) {
            float4 a4[4], b4[8];
#pragma unroll
            for (int r = 0; r < 4; ++r)
                a4[r] = *(const float4*)&region[(ib + tg * 4 + r) * 36 + k4 * 4];
#pragma unroll
            for (int c = 0; c < 8; ++c)
                b4[c] = *(const float4*)&region[(tc + 32 * c) * 36 + k4 * 4];
#pragma unroll
            for (int r = 0; r < 4; ++r)
#pragma unroll
                for (int c = 0; c < 8; ++c)
                    acc[r][c] += a4[r].x * b4[c].x + a4[r].y * b4[c].y +
                                 a4[r].z * b4[c].z + a4[r].w * b4[c].w;
        }
        __syncthreads();
    }

    x2s[t] = x2loc;
    __syncthreads();

#pragma unroll
    for (int r = 0; r < 4; ++r) {
        int ii = tg * 4 + r;
        float xi = x2s[ib + ii];
#pragma unroll
        for (int c = 0; c < 8; ++c) {
            int j = tc + 32 * c;
            float d2 = xi + x2s[j] - 2.f * acc[r][c];
            region[ii * M + j] = sqrtf(fmaxf(d2, 0.f) + 1e-12f);
        }
    }
    __syncthreads();

    const int lane = t & 63;
    const int w    = t >> 6;
    const unsigned long long lmask = (1ull << lane) - 1ull;

    float hardAcc = 0.f;
    float rowSum  = 0.f;

    for (int a = 0; a < 8; ++a) {
        int ii = w * 8 + a;
        int li = lab[ib + ii];
        int runMatch = 0;
        float negmin = 3.4e38f;
        float ndv[4]; int nqv[4]; int nval[4];
#pragma unroll
        for (int ch = 0; ch < 4; ++ch) {
            int j = ch * 64 + lane;
            float d = region[ii * M + j];
            bool match = (lab[j] == li);
            unsigned long long bal = __ballot(match);
            int prefix  = __popcll(bal & lmask);
            int posRank = runMatch + prefix;
            if (match) {
                if (posRank < NPOS) posbuf[w][posRank] = d;
                nval[ch] = 0; ndv[ch] = 0.f; nqv[ch] = 0;
            } else {
                ndv[ch] = d; nqv[ch] = j - posRank; nval[ch] = 1;
                negmin = fminf(negmin, d);
            }
            runMatch += __popcll(bal);
            rowSum += d;
        }
        __syncthreads();

        float maxpos = posbuf[w][0];
#pragma unroll
        for (int pp = 1; pp < NPOS; ++pp) maxpos = fmaxf(maxpos, posbuf[w][pp]);
#pragma unroll
        for (int off = 32; off >= 1; off >>= 1)
            negmin = fminf(negmin, __shfl_xor(negmin, off));
        hardAcc += fmaxf(MARG + maxpos - negmin, 0.f);

#pragma unroll
        for (int ch = 0; ch < 4; ++ch) {
            if (nval[ch]) {
                float dneg = ndv[ch]; int q = nqv[ch];
                float s = 0.f, cnt = 0.f;
#pragma unroll
                for (int pp = 0; pp < NPOS; ++pp) {
                    float v = MARG + posbuf[w][pp] - dneg;
                    if (v > 0.f) { s += v; cnt += 1.f; }
                }
                fullS[w][q] += s;
                fullC[w][q] += cnt;
            }
        }
        __syncthreads();
    }

#pragma unroll
    for (int off = 32; off >= 1; off >>= 1) rowSum += __shfl_xor(rowSum, off);
    if (lane == 0) { wred[w] = hardAcc; wred[4 + w] = rowSum; }
    __syncthreads();

    float* rec = ws + (size_t)bx * REC;
    if (t < NNEG) {
        float s = fullS[0][t] + fullS[1][t] + fullS[2][t] + fullS[3][t];
        float c = fullC[0][t] + fullC[1][t] + fullC[2][t] + fullC[3][t];
        rec[t] = s;
        rec[NNEG + t] = c;
    }
    if (t == 0) {
        rec[496] = wred[0] + wred[1] + wred[2] + wred[3];
        rec[497] = wred[4] + wred[5] + wred[6] + wred[7];
    }
}

__global__ __launch_bounds__(256) void fb_fin(const float* __restrict__ recs,
                                              float* __restrict__ out)
{
    const int p = blockIdx.x;
    const int t = threadIdx.x;
    if (p < NPART) {
        if (t < NNEG) {
            float s = 0.f, c = 0.f;
            for (int a = 0; a < 8; ++a) {
                const float* rec = recs + (size_t)(p * 8 + a) * REC;
                s += rec[t];
                c += rec[NNEG + t];
            }
            out[p * NNEG + t]          = s / (c + 1e-6f);
            out[OFF_FN + p * NNEG + t] = c;
        }
        if (t == 0) {
            float h = 0.f;
            for (int a = 0; a < 8; ++a) h += recs[(size_t)(p * 8 + a) * REC + 496];
            out[OFF_HARD + p] = h * (1.0f / 256.0f);
        }
    } else {
        __shared__ float red[4];
        float v = 0.f;
        for (int i = t; i < 496; i += 256) v += recs[(size_t)i * REC + 497];
#pragma unroll
        for (int off = 32; off >= 1; off >>= 1) v += __shfl_xor(v, off);
        if ((t & 63) == 0) red[t >> 6] = v;
        __syncthreads();
        if (t == 0)
            out[OFF_MD] = (red[0] + red[1] + red[2] + red[3]) / (float)((size_t)NPART * M * M);
    }
}

// ======================= launch =======================
extern "C" void kernel_launch(void* const* d_in, const int* in_sizes, int n_in,
                              void* d_out, int out_size, void* d_ws, size_t ws_size,
                              hipStream_t stream)
{
    const float* F     = (const float*)d_in[0];
    const int*   label = (const int*)d_in[1];
    float*       ws    = (float*)d_ws;
    float*       out   = (float*)d_out;

    if (ws_size >= WS_NEED) {
        k_all<<<dim3(248), dim3(1024), 0, stream>>>(F, label, ws);
        k_fin<<<dim3(63),  dim3(256),  0, stream>>>(ws, out);
    } else {
        fb_main<<<dim3(496), dim3(256), 0, stream>>>(F, label, ws);
        fb_fin <<<dim3(63),  dim3(256), 0, stream>>>(ws, out);
    }
}

// Round 14
// 23.175 us; speedup vs baseline: 1.2464x; 1.0153x over previous
//
#include <hip/hip_runtime.h>

#define NPART 62
#define M     256
#define DD    256
#define NPOS  8
#define NNEG  248
#define MARG  0.2f
#define REC   512

#define WS_NEED ((size_t)(496 * REC) * 4)

#define OFF_HARD 15376
#define OFF_MD   15438
#define OFF_FN   15439

typedef _Float16 f16x8 __attribute__((ext_vector_type(8)));
typedef float    f32x4 __attribute__((ext_vector_type(4)));

#define PITCH 258

// fragment-slot swizzle (both sides): position of (row&15, k-octet g) in a 64-slot tile.
__device__ __forceinline__ int fragpos(int r15, int g) { return (r15 ^ (g << 1)) + (g << 4); }

// ======================= fused convert + staged MFMA dist + mining =======================
// 248 blocks (8 XCD x 31), 1024 threads. Block = (part p, 64-row tile rt4).
// BK=64 slabs = 2 x 32-k sub-slabs (each laid out exactly like R13's proven slab).
__global__ __launch_bounds__(1024) void k_all(const float* __restrict__ F,
                                              const int* __restrict__ label,
                                              float* __restrict__ recs)
{
    // stage: 2 x 32KB f16 slabs (dbuf); later overlaid by dist[64][PITCH] (66,048B)
    __shared__ __align__(16) char smem[64 * PITCH * 4];
    __shared__ float x2s[M];
    __shared__ float fullS[16][NNEG];
    __shared__ float fullC[16][NNEG];
    __shared__ float posbuf[16][NPOS];
    __shared__ float wred[32];

    const int bxr = blockIdx.x;                       // 248 = 8 XCD * 31
    const int swz = (bxr & 7) * 31 + (bxr >> 3);      // bijective; part's 4 tiles same-XCD
    const int p   = swz >> 2;
    const int rt4 = swz & 3;
    const int ib  = rt4 * 64;                         // anchor base (global row)
    const int a0  = rt4 * 4;                          // first A row-tile (of 16)
    const int t   = threadIdx.x;
    const int lane = t & 63;
    const int w    = t >> 6;                          // wave 0..15 = B col-tile

    const float* Fp = F + (size_t)p * (M * DD);

    // staging role: thread t covers (row = t>>2, k-octet = t&3) of each 32-k sub-slab
    const int srow = t >> 2;
    const int soct = t & 3;
    const int stile = srow >> 4;
    const int whalf = ((stile * 64) + fragpos(srow & 15, soct)) * 8;
    const float* gsrc = Fp + srow * DD + soct * 8;

    // compute-side fragment lane position (swizzled, same involution as write side)
    const int flane = fragpos(lane & 15, lane >> 4);

    _Float16* stage0 = (_Float16*)smem;
    _Float16* stage1 = (_Float16*)(smem + 32768);

    f32x4 acc[4];
#pragma unroll
    for (int rt = 0; rt < 4; ++rt) acc[rt] = (f32x4){0.f, 0.f, 0.f, 0.f};

    float x2p = 0.f;

    auto CVT = [&](_Float16* SW, float4 a, float4 b, int u) {
        float xx[8] = {a.x, a.y, a.z, a.w, b.x, b.y, b.z, b.w};
        f16x8 hv;
#pragma unroll
        for (int j = 0; j < 8; ++j) {
            x2p += xx[j] * xx[j];
            hv[j] = (_Float16)xx[j];
        }
        *(f16x8*)(SW + u * 8192 + whalf) = hv;
    };

    // prologue: 64-k slab 0 -> stage0
    {
        float4 a0v = *(const float4*)(gsrc + 0);
        float4 a1v = *(const float4*)(gsrc + 4);
        float4 b0v = *(const float4*)(gsrc + 32);
        float4 b1v = *(const float4*)(gsrc + 36);
        CVT(stage0, a0v, a1v, 0);
        CVT(stage0, b0v, b1v, 1);
    }
    __syncthreads();

#pragma unroll
    for (int P = 0; P < 4; ++P) {
        float4 m0, m1, m2, m3;
        if (P < 3) {                                   // issue next-slab loads early (T14)
            const float* g = gsrc + (P + 1) * 64;
            m0 = *(const float4*)(g + 0);
            m1 = *(const float4*)(g + 4);
            m2 = *(const float4*)(g + 32);
            m3 = *(const float4*)(g + 36);
        }
        // compute the two 32-k sub-slabs of slab P from stage[P&1]
        const _Float16* SB = (P & 1) ? stage1 : stage0;
#pragma unroll
        for (int u = 0; u < 2; ++u) {
            const _Float16* SU = SB + u * 8192;
            f16x8 B = *(const f16x8*)(SU + (w * 64 + flane) * 8);
#pragma unroll
            for (int rt = 0; rt < 4; ++rt) {
                f16x8 A = *(const f16x8*)(SU + ((a0 + rt) * 64 + flane) * 8);
                acc[rt] = __builtin_amdgcn_mfma_f32_16x16x32_f16(A, B, acc[rt], 0, 0, 0);
            }
        }
        if (P < 3) {                                   // convert + write slab P+1 (other buffer)
            _Float16* SW = (P & 1) ? stage0 : stage1;
            CVT(SW, m0, m1, 0);
            CVT(SW, m2, m3, 1);
            __syncthreads();                           // writes visible before next compute
        }
    }

    // ---- x2 (exact fp32): reduce over the 4 octets, publish ----
    x2p += __shfl_xor(x2p, 1);
    x2p += __shfl_xor(x2p, 2);
    if ((lane & 3) == 0) x2s[srow] = x2p;
    __syncthreads();   // x2s ready AND all waves done with stage buffers

    // ---- epilogue: dist -> LDS region (overlays stage); fold block dist-sum here ----
    float* region = (float*)smem;
    const int cbase = lane & 15;
    const int rbase = (lane >> 4) * 4;
    const float xj = x2s[w * 16 + cbase];
    float dsum = 0.f;
#pragma unroll
    for (int rt = 0; rt < 4; ++rt)
#pragma unroll
        for (int r = 0; r < 4; ++r) {
            float xi = x2s[ib + rt * 16 + rbase + r];
            float d2 = xi + xj - 2.f * acc[rt][r];
            float dd = sqrtf(fmaxf(d2, 0.f) + 1e-12f);
            dsum += dd;
            region[(rt * 16 + rbase + r) * PITCH + w * 16 + cbase] = dd;
        }
#pragma unroll
    for (int off = 32; off >= 1; off >>= 1) dsum += __shfl_xor(dsum, off);
    if (lane == 0) wred[16 + w] = dsum;
    __syncthreads();

    // ---- mining: wave-private (wave w owns local anchors w*4..w*4+3) ----
    int llab[4];
#pragma unroll
    for (int ch = 0; ch < 4; ++ch) llab[ch] = label[p * M + ch * 64 + lane];

    for (int idx = lane; idx < NNEG; idx += 64) { fullS[w][idx] = 0.f; fullC[w][idx] = 0.f; }

    const unsigned long long lmask = (1ull << lane) - 1ull;
    float hardAcc = 0.f;

    for (int a = 0; a < 4; ++a) {
        const int ii = w * 4 + a;
        const int li = label[p * M + ib + ii];   // wave-uniform
        int runMatch = 0;
        float negmin = 3.4e38f;
        float ndv[4]; int nqv[4]; int nval[4];
#pragma unroll
        for (int ch = 0; ch < 4; ++ch) {
            const int j = ch * 64 + lane;
            float d = region[ii * PITCH + j];
            bool match = (llab[ch] == li);
            unsigned long long bal = __ballot(match);
            int posRank = runMatch + __popcll(bal & lmask);
            if (match) {
                if (posRank < NPOS) posbuf[w][posRank] = d;
                nval[ch] = 0; ndv[ch] = 0.f; nqv[ch] = 0;
            } else {
                ndv[ch] = d; nqv[ch] = j - posRank; nval[ch] = 1;
                negmin = fminf(negmin, d);
            }
            runMatch += __popcll(bal);
        }
        asm volatile("s_waitcnt lgkmcnt(0)" ::: "memory");  // same-wave posbuf drain

        float maxpos = posbuf[w][0];
#pragma unroll
        for (int pp = 1; pp < NPOS; ++pp) maxpos = fmaxf(maxpos, posbuf[w][pp]);
#pragma unroll
        for (int off = 32; off >= 1; off >>= 1)
            negmin = fminf(negmin, __shfl_xor(negmin, off));
        hardAcc += fmaxf(MARG + maxpos - negmin, 0.f);

#pragma unroll
        for (int ch = 0; ch < 4; ++ch) {
            if (nval[ch]) {
                float dneg = ndv[ch]; int q = nqv[ch];
                float s = 0.f, cnt = 0.f;
#pragma unroll
                for (int pp = 0; pp < NPOS; ++pp) {
                    float v = MARG + posbuf[w][pp] - dneg;
                    s   += fmaxf(v, 0.f);
                    cnt += (v > 0.f) ? 1.f : 0.f;
                }
                fullS[w][q] += s;   // per-wave private; q distinct per lane
                fullC[w][q] += cnt;
            }
        }
    }

    if (lane == 0) wred[w] = hardAcc;
    __syncthreads();

    float* rec = recs + (size_t)swz * REC;
    if (t < NNEG) {
        float s = 0.f, c = 0.f;
#pragma unroll
        for (int v = 0; v < 16; ++v) { s += fullS[v][t]; c += fullC[v][t]; }
        rec[t] = s;
        rec[NNEG + t] = c;
    }
    if (t == 0) {
        float h = 0.f, ds = 0.f;
#pragma unroll
        for (int v = 0; v < 16; ++v) { h += wred[v]; ds += wred[16 + v]; }
        rec[496] = h;
        rec[497] = ds;
    }
}

// ======================= merged finalize: 63 blocks, 4 recs/part =======================
__global__ __launch_bounds__(256) void k_fin(const float* __restrict__ recs,
                                             float* __restrict__ out)
{
    const int p = blockIdx.x;
    const int t = threadIdx.x;
    if (p < NPART) {
        if (t < NNEG) {
            float s = 0.f, c = 0.f;
#pragma unroll
            for (int a = 0; a < 4; ++a) {
                const float* rec = recs + (size_t)(p * 4 + a) * REC;
                s += rec[t];
                c += rec[NNEG + t];
            }
            out[p * NNEG + t]          = s / (c + 1e-6f);
            out[OFF_FN + p * NNEG + t] = c;
        }
        if (t == 0) {
            float h = 0.f;
#pragma unroll
            for (int a = 0; a < 4; ++a) h += recs[(size_t)(p * 4 + a) * REC + 496];
            out[OFF_HARD + p] = h * (1.0f / 256.0f);
        }
    } else {
        __shared__ float red[4];
        float v = (t < 248) ? recs[(size_t)t * REC + 497] : 0.f;
#pragma unroll
        for (int off = 32; off >= 1; off >>= 1) v += __shfl_xor(v, off);
        if ((t & 63) == 0) red[t >> 6] = v;
        __syncthreads();
        if (t == 0)
            out[OFF_MD] = (red[0] + red[1] + red[2] + red[3]) / (float)((size_t)NPART * M * M);
    }
}

// ======================= fallback: proven round-1 fused path =======================
__global__ __launch_bounds__(256) void fb_main(
    const float* __restrict__ F, const int* __restrict__ label, float* __restrict__ ws)
{
    __shared__ __align__(16) float region[256 * 36];
    __shared__ float x2s[M];
    __shared__ int   lab[M];
    __shared__ float posbuf[4][NPOS];
    __shared__ float fullS[4][NNEG];
    __shared__ float fullC[4][NNEG];
    __shared__ float wred[8];

    const int bx = blockIdx.x;
    const int p  = bx >> 3;
    const int ib = (bx & 7) * 32;
    const int t  = threadIdx.x;

    lab[t] = label[p * M + t];
    for (int idx = t; idx < 4 * NNEG; idx += 256) {
        (&fullS[0][0])[idx] = 0.f;
        (&fullC[0][0])[idx] = 0.f;
    }
    __syncthreads();

    const float4* Fv = (const float4*)(F + (size_t)p * (M * DD));

    float acc[4][8];
#pragma unroll
    for (int r = 0; r < 4; ++r)
#pragma unroll
        for (int c = 0; c < 8; ++c) acc[r][c] = 0.f;

    float x2loc = 0.f;
    const int tc = t & 31;
    const int tg = t >> 5;

    for (int kt = 0; kt < 8; ++kt) {
#pragma unroll
        for (int w = 0; w < 8; ++w) {
            int ch = w * 256 + t;
            int r  = ch >> 3;
            int q  = ch & 7;
            float4 v = Fv[r * 64 + kt * 8 + q];
            float* dst = &region[r * 36 + q * 4];
            dst[0] = v.x; dst[1] = v.y; dst[2] = v.z; dst[3] = v.w;
        }
        __syncthreads();
#pragma unroll
        for (int k4 = 0; k4 < 8; ++k4) {
            float4 b = *(const float4*)&region[t * 36 + k4 * 4];
            x2loc += b.x * b.x + b.y * b.y + b.z * b.z + b.w * b.w;
        }
#pragma unroll
        for (int k4 = 0; k4 < 8; ++k4) {
            float4 a4[4], b4[8];
#pragma unroll
            for (int r = 0; r < 4; ++r)
                a4[r] = *(const float4*)&region[(ib + tg * 4 + r) * 36 + k4 * 4];
#pragma unroll
            for (int c = 0; c < 8; ++c)
                b4[c] = *(const float4*)&region[(tc + 32 * c) * 36 + k4 * 4];
#pragma unroll
            for (int r = 0; r < 4; ++r)
#pragma unroll
                for (int c = 0; c < 8; ++c)
                    acc[r][c] += a4[r].x * b4[c].x + a4[r].y * b4[c].y +
                                 a4[r].z * b4[c].z + a4[r].w * b4[c].w;
        }
        __syncthreads();
    }

    x2s[t] = x2loc;
    __syncthreads();

#pragma unroll
    for (int r = 0; r < 4; ++r) {
        int ii = tg * 4 + r;
        float xi = x2s[ib + ii];
#pragma unroll
        for (int c = 0; c < 8; ++c) {
            int j = tc + 32 * c;
            float d2 = xi + x2s[j] - 2.f * acc[r][c];
            region[ii * M + j] = sqrtf(fmaxf(d2, 0.f) + 1e-12f);
        }
    }
    __syncthreads();

    const int lane = t & 63;
    const int w    = t >> 6;
    const unsigned long long lmask = (1ull << lane) - 1ull;

    float hardAcc = 0.f;
    float rowSum  = 0.f;

    for (int a = 0; a < 8; ++a) {
        int ii = w * 8 + a;
        int li = lab[ib + ii];
        int runMatch = 0;
        float negmin = 3.4e38f;
        float ndv[4]; int nqv[4]; int nval[4];
#pragma unroll
        for (int ch = 0; ch < 4; ++ch) {
            int j = ch * 64 + lane;
            float d = region[ii * M + j];
            bool match = (lab[j] == li);
            unsigned long long bal = __ballot(match);
            int prefix  = __popcll(bal & lmask);
            int posRank = runMatch + prefix;
            if (match) {
                if (posRank < NPOS) posbuf[w][posRank] = d;
                nval[ch] = 0; ndv[ch] = 0.f; nqv[ch] = 0;
            } else {
                ndv[ch] = d; nqv[ch] = j - posRank; nval[ch] = 1;
                negmin = fminf(negmin, d);
            }
            runMatch += __popcll(bal);
            rowSum += d;
        }
        __syncthreads();

        float maxpos = posbuf[w][0];
#pragma unroll
        for (int pp = 1; pp < NPOS; ++pp) maxpos = fmaxf(maxpos, posbuf[w][pp]);
#pragma unroll
        for (int off = 32; off >= 1; off >>= 1)
            negmin = fminf(negmin, __shfl_xor(negmin, off));
        hardAcc += fmaxf(MARG + maxpos - negmin, 0.f);

#pragma unroll
        for (int ch = 0; ch < 4; ++ch) {
            if (nval[ch]) {
                float dneg = ndv[ch]; int q = nqv[ch];
                float s = 0.f, cnt = 0.f;
#pragma unroll
                for (int pp = 0; pp < NPOS; ++pp) {
                    float v = MARG + posbuf[w][pp] - dneg;
                    if (v > 0.f) { s += v; cnt += 1.f; }
                }
                fullS[w][q] += s;
                fullC[w][q] += cnt;
            }
        }
        __syncthreads();
    }

#pragma unroll
    for (int off = 32; off >= 1; off >>= 1) rowSum += __shfl_xor(rowSum, off);
    if (lane == 0) { wred[w] = hardAcc; wred[4 + w] = rowSum; }
    __syncthreads();

    float* rec = ws + (size_t)bx * REC;
    if (t < NNEG) {
        float s = fullS[0][t] + fullS[1][t] + fullS[2][t] + fullS[3][t];
        float c = fullC[0][t] + fullC[1][t] + fullC[2][t] + fullC[3][t];
        rec[t] = s;
        rec[NNEG + t] = c;
    }
    if (t == 0) {
        rec[496] = wred[0] + wred[1] + wred[2] + wred[3];
        rec[497] = wred[4] + wred[5] + wred[6] + wred[7];
    }
}

__global__ __launch_bounds__(256) void fb_fin(const float* __restrict__ recs,
                                              float* __restrict__ out)
{
    const int p = blockIdx.x;
    const int t = threadIdx.x;
    if (p < NPART) {
        if (t < NNEG) {
            float s = 0.f, c = 0.f;
            for (int a = 0; a < 8; ++a) {
                const float* rec = recs + (size_t)(p * 8 + a) * REC;
                s += rec[t];
                c += rec[NNEG + t];
            }
            out[p * NNEG + t]          = s / (c + 1e-6f);
            out[OFF_FN + p * NNEG + t] = c;
        }
        if (t == 0) {
            float h = 0.f;
            for (int a = 0; a < 8; ++a) h += recs[(size_t)(p * 8 + a) * REC + 496];
            out[OFF_HARD + p] = h * (1.0f / 256.0f);
        }
    } else {
        __shared__ float red[4];
        float v = 0.f;
        for (int i = t; i < 496; i += 256) v += recs[(size_t)i * REC + 497];
#pragma unroll
        for (int off = 32; off >= 1; off >>= 1) v += __shfl_xor(v, off);
        if ((t & 63) == 0) red[t >> 6] = v;
        __syncthreads();
        if (t == 0)
            out[OFF_MD] = (red[0] + red[1] + red[2] + red[3]) / (float)((size_t)NPART * M * M);
    }
}

// ======================= launch =======================
extern "C" void kernel_launch(void* const* d_in, const int* in_sizes, int n_in,
                              void* d_out, int out_size, void* d_ws, size_t ws_size,
                              hipStream_t stream)
{
    const float* F     = (const float*)d_in[0];
    const int*   label = (const int*)d_in[1];
    float*       ws    = (float*)d_ws;
    float*       out   = (float*)d_out;

    if (ws_size >= WS_NEED) {
        k_all<<<dim3(248), dim3(1024), 0, stream>>>(F, label, ws);
        k_fin<<<dim3(63),  dim3(256),  0, stream>>>(ws, out);
    } else {
        fb_main<<<dim3(496), dim3(256), 0, stream>>>(F, label, ws);
        fb_fin <<<dim3(63),  dim3(256), 0, stream>>>(ws, out);
    }
}

// Round 15
// 22.758 us; speedup vs baseline: 1.2692x; 1.0183x over previous
//
#include <hip/hip_runtime.h>

#define NPART 62
#define M     256
#define DD    256
#define NPOS  8
#define NNEG  248
#define MARG  0.2f
#define REC   512

#define WS_NEED ((size_t)(496 * REC) * 4)

#define OFF_HARD 15376
#define OFF_MD   15438
#define OFF_FN   15439

typedef _Float16 f16x8 __attribute__((ext_vector_type(8)));
typedef float    f32x4 __attribute__((ext_vector_type(4)));

#define PITCH 258

// fragment-slot swizzle (both sides): position of (row&15, k-octet g) in a 64-slot tile.
__device__ __forceinline__ int fragpos(int r15, int g) { return (r15 ^ (g << 1)) + (g << 4); }

// ======================= fused convert + staged MFMA dist + mining =======================
// 248 blocks (8 XCD x 31), 1024 threads. Block = (part p, 64-row tile rt4).
// BK=64 slabs = 2 x 32-k sub-slabs. Wave grid 2x8: wave w -> row-tiles {a0+2wr,+1},
// col-tiles {2wc,+1} -> 4 LDS reads + 4 MFMAs per sub-slab (vs 5 reads at 1x16).
__global__ __launch_bounds__(1024) void k_all(const float* __restrict__ F,
                                              const int* __restrict__ label,
                                              float* __restrict__ recs)
{
    // stage: 2 x 32KB f16 slabs (dbuf); later overlaid by dist[64][PITCH] (66,048B)
    __shared__ __align__(16) char smem[64 * PITCH * 4];
    __shared__ float x2s[M];
    __shared__ float fullS[16][NNEG];
    __shared__ float fullC[16][NNEG];
    __shared__ float posbuf[16][NPOS];
    __shared__ float wred[32];

    const int bxr = blockIdx.x;                       // 248 = 8 XCD * 31
    const int swz = (bxr & 7) * 31 + (bxr >> 3);      // bijective; part's 4 tiles same-XCD
    const int p   = swz >> 2;
    const int rt4 = swz & 3;
    const int ib  = rt4 * 64;                         // anchor base (global row)
    const int a0  = rt4 * 4;                          // first A row-tile (of 16)
    const int t   = threadIdx.x;
    const int lane = t & 63;
    const int w    = t >> 6;                          // wave 0..15
    const int wr   = w >> 3;                          // row-pair 0..1
    const int wc   = w & 7;                           // col-pair 0..7

    const float* Fp = F + (size_t)p * (M * DD);

    // staging role: thread t covers (row = t>>2, k-octet = t&3) of each 32-k sub-slab
    const int srow = t >> 2;
    const int soct = t & 3;
    const int stile = srow >> 4;
    const int whalf = ((stile * 64) + fragpos(srow & 15, soct)) * 8;
    const float* gsrc = Fp + srow * DD + soct * 8;

    // compute-side fragment lane position (swizzled, same involution as write side)
    const int flane = fragpos(lane & 15, lane >> 4);

    _Float16* stage0 = (_Float16*)smem;
    _Float16* stage1 = (_Float16*)(smem + 32768);

    // ---- hoisted mining setup: latency hides under staging ----
    int llab[4], lli[4];
#pragma unroll
    for (int ch = 0; ch < 4; ++ch) llab[ch] = label[p * M + ch * 64 + lane];
#pragma unroll
    for (int a = 0; a < 4; ++a) lli[a] = label[p * M + ib + w * 4 + a];
    for (int idx = lane; idx < NNEG; idx += 64) { fullS[w][idx] = 0.f; fullC[w][idx] = 0.f; }

    f32x4 acc[2][2];
#pragma unroll
    for (int i = 0; i < 2; ++i)
#pragma unroll
        for (int j = 0; j < 2; ++j) acc[i][j] = (f32x4){0.f, 0.f, 0.f, 0.f};

    float x2p = 0.f;

    auto CVT = [&](_Float16* SW, float4 a, float4 b, int u) {
        float xx[8] = {a.x, a.y, a.z, a.w, b.x, b.y, b.z, b.w};
        f16x8 hv;
#pragma unroll
        for (int j = 0; j < 8; ++j) {
            x2p += xx[j] * xx[j];
            hv[j] = (_Float16)xx[j];
        }
        *(f16x8*)(SW + u * 8192 + whalf) = hv;
    };

    // prologue: 64-k slab 0 -> stage0
    {
        float4 a0v = *(const float4*)(gsrc + 0);
        float4 a1v = *(const float4*)(gsrc + 4);
        float4 b0v = *(const float4*)(gsrc + 32);
        float4 b1v = *(const float4*)(gsrc + 36);
        CVT(stage0, a0v, a1v, 0);
        CVT(stage0, b0v, b1v, 1);
    }
    __syncthreads();

#pragma unroll
    for (int P = 0; P < 4; ++P) {
        float4 m0, m1, m2, m3;
        if (P < 3) {                                   // issue next-slab loads early (T14)
            const float* g = gsrc + (P + 1) * 64;
            m0 = *(const float4*)(g + 0);
            m1 = *(const float4*)(g + 4);
            m2 = *(const float4*)(g + 32);
            m3 = *(const float4*)(g + 36);
        }
        // compute the two 32-k sub-slabs of slab P from stage[P&1]
        const _Float16* SB = (P & 1) ? stage1 : stage0;
#pragma unroll
        for (int u = 0; u < 2; ++u) {
            const _Float16* SU = SB + u * 8192;
            f16x8 A[2], B[2];
#pragma unroll
            for (int i = 0; i < 2; ++i)
                A[i] = *(const f16x8*)(SU + ((a0 + 2 * wr + i) * 64 + flane) * 8);
#pragma unroll
            for (int j = 0; j < 2; ++j)
                B[j] = *(const f16x8*)(SU + ((2 * wc + j) * 64 + flane) * 8);
#pragma unroll
            for (int i = 0; i < 2; ++i)
#pragma unroll
                for (int j = 0; j < 2; ++j)
                    acc[i][j] = __builtin_amdgcn_mfma_f32_16x16x32_f16(A[i], B[j], acc[i][j], 0, 0, 0);
        }
        if (P < 3) {                                   // convert + write slab P+1 (other buffer)
            _Float16* SW = (P & 1) ? stage0 : stage1;
            CVT(SW, m0, m1, 0);
            CVT(SW, m2, m3, 1);
            __syncthreads();                           // writes visible before next compute
        }
    }

    // ---- x2 (exact fp32): reduce over the 4 octets, publish ----
    x2p += __shfl_xor(x2p, 1);
    x2p += __shfl_xor(x2p, 2);
    if ((lane & 3) == 0) x2s[srow] = x2p;
    __syncthreads();   // x2s ready AND all waves done with stage buffers

    // ---- epilogue: dist -> LDS region (overlays stage); fold block dist-sum here ----
    float* region = (float*)smem;
    const int cbase = lane & 15;
    const int rbase = (lane >> 4) * 4;
    float dsum = 0.f;
#pragma unroll
    for (int i = 0; i < 2; ++i)
#pragma unroll
        for (int j = 0; j < 2; ++j) {
            const int lrt = 2 * wr + i;
            const float xj = x2s[(2 * wc + j) * 16 + cbase];
#pragma unroll
            for (int r = 0; r < 4; ++r) {
                int lrow = lrt * 16 + rbase + r;
                float xi = x2s[ib + lrow];
                float d2 = xi + xj - 2.f * acc[i][j][r];
                float dd = sqrtf(fmaxf(d2, 0.f) + 1e-12f);
                dsum += dd;
                region[lrow * PITCH + (2 * wc + j) * 16 + cbase] = dd;
            }
        }
#pragma unroll
    for (int off = 32; off >= 1; off >>= 1) dsum += __shfl_xor(dsum, off);
    if (lane == 0) wred[16 + w] = dsum;
    __syncthreads();

    // ---- mining: wave-private (wave w owns local anchors w*4..w*4+3) ----
    const unsigned long long lmask = (1ull << lane) - 1ull;
    float hardAcc = 0.f;

    for (int a = 0; a < 4; ++a) {
        const int ii = w * 4 + a;
        const int li = lli[a];                    // wave-uniform (hoisted)
        int runMatch = 0;
        float negmin = 3.4e38f;
        float ndv[4]; int nqv[4]; int nval[4];
#pragma unroll
        for (int ch = 0; ch < 4; ++ch) {
            const int j = ch * 64 + lane;
            float d = region[ii * PITCH + j];
            bool match = (llab[ch] == li);
            unsigned long long bal = __ballot(match);
            int posRank = runMatch + __popcll(bal & lmask);
            if (match) {
                if (posRank < NPOS) posbuf[w][posRank] = d;
                nval[ch] = 0; ndv[ch] = 0.f; nqv[ch] = 0;
            } else {
                ndv[ch] = d; nqv[ch] = j - posRank; nval[ch] = 1;
                negmin = fminf(negmin, d);
            }
            runMatch += __popcll(bal);
        }
        asm volatile("s_waitcnt lgkmcnt(0)" ::: "memory");  // same-wave posbuf drain

        float maxpos = posbuf[w][0];
#pragma unroll
        for (int pp = 1; pp < NPOS; ++pp) maxpos = fmaxf(maxpos, posbuf[w][pp]);
#pragma unroll
        for (int off = 32; off >= 1; off >>= 1)
            negmin = fminf(negmin, __shfl_xor(negmin, off));
        hardAcc += fmaxf(MARG + maxpos - negmin, 0.f);

#pragma unroll
        for (int ch = 0; ch < 4; ++ch) {
            if (nval[ch]) {
                float dneg = ndv[ch]; int q = nqv[ch];
                float s = 0.f, cnt = 0.f;
#pragma unroll
                for (int pp = 0; pp < NPOS; ++pp) {
                    float v = MARG + posbuf[w][pp] - dneg;
                    s   += fmaxf(v, 0.f);
                    cnt += (v > 0.f) ? 1.f : 0.f;
                }
                fullS[w][q] += s;   // per-wave private; q distinct per lane
                fullC[w][q] += cnt;
            }
        }
    }

    if (lane == 0) wred[w] = hardAcc;
    __syncthreads();

    float* rec = recs + (size_t)swz * REC;
    if (t < NNEG) {
        float s = 0.f, c = 0.f;
#pragma unroll
        for (int v = 0; v < 16; ++v) { s += fullS[v][t]; c += fullC[v][t]; }
        rec[t] = s;
        rec[NNEG + t] = c;
    }
    if (t == 0) {
        float h = 0.f, ds = 0.f;
#pragma unroll
        for (int v = 0; v < 16; ++v) { h += wred[v]; ds += wred[16 + v]; }
        rec[496] = h;
        rec[497] = ds;
    }
}

// ======================= merged finalize: 63 blocks, 4 recs/part =======================
__global__ __launch_bounds__(256) void k_fin(const float* __restrict__ recs,
                                             float* __restrict__ out)
{
    const int p = blockIdx.x;
    const int t = threadIdx.x;
    if (p < NPART) {
        if (t < NNEG) {
            float s = 0.f, c = 0.f;
#pragma unroll
            for (int a = 0; a < 4; ++a) {
                const float* rec = recs + (size_t)(p * 4 + a) * REC;
                s += rec[t];
                c += rec[NNEG + t];
            }
            out[p * NNEG + t]          = s / (c + 1e-6f);
            out[OFF_FN + p * NNEG + t] = c;
        }
        if (t == 0) {
            float h = 0.f;
#pragma unroll
            for (int a = 0; a < 4; ++a) h += recs[(size_t)(p * 4 + a) * REC + 496];
            out[OFF_HARD + p] = h * (1.0f / 256.0f);
        }
    } else {
        __shared__ float red[4];
        float v = (t < 248) ? recs[(size_t)t * REC + 497] : 0.f;
#pragma unroll
        for (int off = 32; off >= 1; off >>= 1) v += __shfl_xor(v, off);
        if ((t & 63) == 0) red[t >> 6] = v;
        __syncthreads();
        if (t == 0)
            out[OFF_MD] = (red[0] + red[1] + red[2] + red[3]) / (float)((size_t)NPART * M * M);
    }
}

// ======================= fallback: proven round-1 fused path =======================
__global__ __launch_bounds__(256) void fb_main(
    const float* __restrict__ F, const int* __restrict__ label, float* __restrict__ ws)
{
    __shared__ __align__(16) float region[256 * 36];
    __shared__ float x2s[M];
    __shared__ int   lab[M];
    __shared__ float posbuf[4][NPOS];
    __shared__ float fullS[4][NNEG];
    __shared__ float fullC[4][NNEG];
    __shared__ float wred[8];

    const int bx = blockIdx.x;
    const int p  = bx >> 3;
    const int ib = (bx & 7) * 32;
    const int t  = threadIdx.x;

    lab[t] = label[p * M + t];
    for (int idx = t; idx < 4 * NNEG; idx += 256) {
        (&fullS[0][0])[idx] = 0.f;
        (&fullC[0][0])[idx] = 0.f;
    }
    __syncthreads();

    const float4* Fv = (const float4*)(F + (size_t)p * (M * DD));

    float acc[4][8];
#pragma unroll
    for (int r = 0; r < 4; ++r)
#pragma unroll
        for (int c = 0; c < 8; ++c) acc[r][c] = 0.f;

    float x2loc = 0.f;
    const int tc = t & 31;
    const int tg = t >> 5;

    for (int kt = 0; kt < 8; ++kt) {
#pragma unroll
        for (int w = 0; w < 8; ++w) {
            int ch = w * 256 + t;
            int r  = ch >> 3;
            int q  = ch & 7;
            float4 v = Fv[r * 64 + kt * 8 + q];
            float* dst = &region[r * 36 + q * 4];
            dst[0] = v.x; dst[1] = v.y; dst[2] = v.z; dst[3] = v.w;
        }
        __syncthreads();
#pragma unroll
        for (int k4 = 0; k4 < 8; ++k4) {
            float4 b = *(const float4*)&region[t * 36 + k4 * 4];
            x2loc += b.x * b.x + b.y * b.y + b.z * b.z + b.w * b.w;
        }
#pragma unroll
        for (int k4 = 0; k4 < 8; ++k4) {
            float4 a4[4], b4[8];
#pragma unroll
            for (int r = 0; r < 4; ++r)
                a4[r] = *(const float4*)&region[(ib + tg * 4 + r) * 36 + k4 * 4];
#pragma unroll
            for (int c = 0; c < 8; ++c)
                b4[c] = *(const float4*)&region[(tc + 32 * c) * 36 + k4 * 4];
#pragma unroll
            for (int r = 0; r < 4; ++r)
#pragma unroll
                for (int c = 0; c < 8; ++c)
                    acc[r][c] += a4[r].x * b4[c].x + a4[r].y * b4[c].y +
                                 a4[r].z * b4[c].z + a4[r].w * b4[c].w;
        }
        __syncthreads();
    }

    x2s[t] = x2loc;
    __syncthreads();

#pragma unroll
    for (int r = 0; r < 4; ++r) {
        int ii = tg * 4 + r;
        float xi = x2s[ib + ii];
#pragma unroll
        for (int c = 0; c < 8; ++c) {
            int j = tc + 32 * c;
            float d2 = xi + x2s[j] - 2.f * acc[r][c];
            region[ii * M + j] = sqrtf(fmaxf(d2, 0.f) + 1e-12f);
        }
    }
    __syncthreads();

    const int lane = t & 63;
    const int w    = t >> 6;
    const unsigned long long lmask = (1ull << lane) - 1ull;

    float hardAcc = 0.f;
    float rowSum  = 0.f;

    for (int a = 0; a < 8; ++a) {
        int ii = w * 8 + a;
        int li = lab[ib + ii];
        int runMatch = 0;
        float negmin = 3.4e38f;
        float ndv[4]; int nqv[4]; int nval[4];
#pragma unroll
        for (int ch = 0; ch < 4; ++ch) {
            int j = ch * 64 + lane;
            float d = region[ii * M + j];
            bool match = (lab[j] == li);
            unsigned long long bal = __ballot(match);
            int prefix  = __popcll(bal & lmask);
            int posRank = runMatch + prefix;
            if (match) {
                if (posRank < NPOS) posbuf[w][posRank] = d;
                nval[ch] = 0; ndv[ch] = 0.f; nqv[ch] = 0;
            } else {
                ndv[ch] = d; nqv[ch] = j - posRank; nval[ch] = 1;
                negmin = fminf(negmin, d);
            }
            runMatch += __popcll(bal);
            rowSum += d;
        }
        __syncthreads();

        float maxpos = posbuf[w][0];
#pragma unroll
        for (int pp = 1; pp < NPOS; ++pp) maxpos = fmaxf(maxpos, posbuf[w][pp]);
#pragma unroll
        for (int off = 32; off >= 1; off >>= 1)
            negmin = fminf(negmin, __shfl_xor(negmin, off));
        hardAcc += fmaxf(MARG + maxpos - negmin, 0.f);

#pragma unroll
        for (int ch = 0; ch < 4; ++ch) {
            if (nval[ch]) {
                float dneg = ndv[ch]; int q = nqv[ch];
                float s = 0.f, cnt = 0.f;
#pragma unroll
                for (int pp = 0; pp < NPOS; ++pp) {
                    float v = MARG + posbuf[w][pp] - dneg;
                    if (v > 0.f) { s += v; cnt += 1.f; }
                }
                fullS[w][q] += s;
                fullC[w][q] += cnt;
            }
        }
        __syncthreads();
    }

#pragma unroll
    for (int off = 32; off >= 1; off >>= 1) rowSum += __shfl_xor(rowSum, off);
    if (lane == 0) { wred[w] = hardAcc; wred[4 + w] = rowSum; }
    __syncthreads();

    float* rec = ws + (size_t)bx * REC;
    if (t < NNEG) {
        float s = fullS[0][t] + fullS[1][t] + fullS[2][t] + fullS[3][t];
        float c = fullC[0][t] + fullC[1][t] + fullC[2][t] + fullC[3][t];
        rec[t] = s;
        rec[NNEG + t] = c;
    }
    if (t == 0) {
        rec[496] = wred[0] + wred[1] + wred[2] + wred[3];
        rec[497] = wred[4] + wred[5] + wred[6] + wred[7];
    }
}

__global__ __launch_bounds__(256) void fb_fin(const float* __restrict__ recs,
                                              float* __restrict__ out)
{
    const int p = blockIdx.x;
    const int t = threadIdx.x;
    if (p < NPART) {
        if (t < NNEG) {
            float s = 0.f, c = 0.f;
            for (int a = 0; a < 8; ++a) {
                const float* rec = recs + (size_t)(p * 8 + a) * REC;
                s += rec[t];
                c += rec[NNEG + t];
            }
            out[p * NNEG + t]          = s / (c + 1e-6f);
            out[OFF_FN + p * NNEG + t] = c;
        }
        if (t == 0) {
            float h = 0.f;
            for (int a = 0; a < 8; ++a) h += recs[(size_t)(p * 8 + a) * REC + 496];
            out[OFF_HARD + p] = h * (1.0f / 256.0f);
        }
    } else {
        __shared__ float red[4];
        float v = 0.f;
        for (int i = t; i < 496; i += 256) v += recs[(size_t)i * REC + 497];
#pragma unroll
        for (int off = 32; off >= 1; off >>= 1) v += __shfl_xor(v, off);
        if ((t & 63) == 0) red[t >> 6] = v;
        __syncthreads();
        if (t == 0)
            out[OFF_MD] = (red[0] + red[1] + red[2] + red[3]) / (float)((size_t)NPART * M * M);
    }
}

// ======================= launch =======================
extern "C" void kernel_launch(void* const* d_in, const int* in_sizes, int n_in,
                              void* d_out, int out_size, void* d_ws, size_t ws_size,
                              hipStream_t stream)
{
    const float* F     = (const float*)d_in[0];
    const int*   label = (const int*)d_in[1];
    float*       ws    = (float*)d_ws;
    float*       out   = (float*)d_out;

    if (ws_size >= WS_NEED) {
        k_all<<<dim3(248), dim3(1024), 0, stream>>>(F, label, ws);
        k_fin<<<dim3(63),  dim3(256),  0, stream>>>(ws, out);
    } else {
        fb_main<<<dim3(496), dim3(256), 0, stream>>>(F, label, ws);
        fb_fin <<<dim3(63),  dim3(256), 0, stream>>>(ws, out);
    }
}

// Round 16
// 22.521 us; speedup vs baseline: 1.2826x; 1.0105x over previous
//
#include <hip/hip_runtime.h>

#define NPART 62
#define M     256
#define DD    256
#define NPOS  8
#define NNEG  248
#define MARG  0.2f
#define REC   512

#define WS_NEED ((size_t)(496 * REC) * 4)

#define OFF_HARD 15376
#define OFF_MD   15438
#define OFF_FN   15439

typedef _Float16 f16x8 __attribute__((ext_vector_type(8)));
typedef float    f32x4 __attribute__((ext_vector_type(4)));

#define PITCH 258

// fragment-slot swizzle (both sides): position of (row&15, k-octet g) in a 64-slot tile.
__device__ __forceinline__ int fragpos(int r15, int g) { return (r15 ^ (g << 1)) + (g << 4); }

// ======================= fused convert + staged MFMA dist + mining =======================
// 248 blocks (8 XCD x 31), 1024 threads. Block = (part p, 64-row tile rt4).
// BK=64 slabs = 2 x 32-k sub-slabs. Wave grid 2x8: wave w -> row-tiles {a0+2wr,+1},
// col-tiles {2wc,+1} -> 4 LDS reads + 4 MFMAs per sub-slab.
__global__ __launch_bounds__(1024) void k_all(const float* __restrict__ F,
                                              const int* __restrict__ label,
                                              float* __restrict__ recs)
{
    // stage: 2 x 32KB f16 slabs (dbuf); later overlaid by dist[64][PITCH] (66,048B)
    __shared__ __align__(16) char smem[64 * PITCH * 4];
    __shared__ float x2s[M];
    __shared__ float fullS[16][NNEG];
    __shared__ float fullC[16][NNEG];
    __shared__ float posbuf[16][NPOS];
    __shared__ float wred[32];

    const int bxr = blockIdx.x;                       // 248 = 8 XCD * 31
    const int swz = (bxr & 7) * 31 + (bxr >> 3);      // bijective; part's 4 tiles same-XCD
    const int p   = swz >> 2;
    const int rt4 = swz & 3;
    const int ib  = rt4 * 64;                         // anchor base (global row)
    const int a0  = rt4 * 4;                          // first A row-tile (of 16)
    const int t   = threadIdx.x;
    const int lane = t & 63;
    const int w    = t >> 6;                          // wave 0..15
    const int wr   = w >> 3;                          // row-pair 0..1
    const int wc   = w & 7;                           // col-pair 0..7

    const float* Fp = F + (size_t)p * (M * DD);

    // staging role: thread t covers (row = t>>2, k-octet = t&3) of each 32-k sub-slab
    const int srow = t >> 2;
    const int soct = t & 3;
    const int stile = srow >> 4;
    const int whalf = ((stile * 64) + fragpos(srow & 15, soct)) * 8;
    const float* gsrc = Fp + srow * DD + soct * 8;

    // compute-side fragment lane position (swizzled, same involution as write side)
    const int flane = fragpos(lane & 15, lane >> 4);

    _Float16* stage0 = (_Float16*)smem;
    _Float16* stage1 = (_Float16*)(smem + 32768);

    // ---- hoisted mining setup: latency hides under staging ----
    int llab[4], lli[4];
#pragma unroll
    for (int ch = 0; ch < 4; ++ch) llab[ch] = label[p * M + ch * 64 + lane];
#pragma unroll
    for (int a = 0; a < 4; ++a) lli[a] = label[p * M + ib + w * 4 + a];
    for (int idx = lane; idx < NNEG; idx += 64) { fullS[w][idx] = 0.f; fullC[w][idx] = 0.f; }

    f32x4 acc[2][2];
#pragma unroll
    for (int i = 0; i < 2; ++i)
#pragma unroll
        for (int j = 0; j < 2; ++j) acc[i][j] = (f32x4){0.f, 0.f, 0.f, 0.f};

    float x2p = 0.f;

    auto CVT = [&](_Float16* SW, float4 a, float4 b, int u) {
        float xx[8] = {a.x, a.y, a.z, a.w, b.x, b.y, b.z, b.w};
        f16x8 hv;
#pragma unroll
        for (int j = 0; j < 8; ++j) {
            x2p += xx[j] * xx[j];
            hv[j] = (_Float16)xx[j];
        }
        *(f16x8*)(SW + u * 8192 + whalf) = hv;
    };

    // prologue: 64-k slab 0 -> stage0
    {
        float4 a0v = *(const float4*)(gsrc + 0);
        float4 a1v = *(const float4*)(gsrc + 4);
        float4 b0v = *(const float4*)(gsrc + 32);
        float4 b1v = *(const float4*)(gsrc + 36);
        CVT(stage0, a0v, a1v, 0);
        CVT(stage0, b0v, b1v, 1);
    }
    __syncthreads();

#pragma unroll
    for (int P = 0; P < 4; ++P) {
        float4 m0, m1, m2, m3;
        if (P < 3) {                                   // issue next-slab loads early (T14)
            const float* g = gsrc + (P + 1) * 64;
            m0 = *(const float4*)(g + 0);
            m1 = *(const float4*)(g + 4);
            m2 = *(const float4*)(g + 32);
            m3 = *(const float4*)(g + 36);
        }
        // compute the two 32-k sub-slabs of slab P from stage[P&1]
        const _Float16* SB = (P & 1) ? stage1 : stage0;
#pragma unroll
        for (int u = 0; u < 2; ++u) {
            const _Float16* SU = SB + u * 8192;
            f16x8 A[2], B[2];
#pragma unroll
            for (int i = 0; i < 2; ++i)
                A[i] = *(const f16x8*)(SU + ((a0 + 2 * wr + i) * 64 + flane) * 8);
#pragma unroll
            for (int j = 0; j < 2; ++j)
                B[j] = *(const f16x8*)(SU + ((2 * wc + j) * 64 + flane) * 8);
#pragma unroll
            for (int i = 0; i < 2; ++i)
#pragma unroll
                for (int j = 0; j < 2; ++j)
                    acc[i][j] = __builtin_amdgcn_mfma_f32_16x16x32_f16(A[i], B[j], acc[i][j], 0, 0, 0);
        }
        if (P < 3) {                                   // convert + write slab P+1 (other buffer)
            _Float16* SW = (P & 1) ? stage0 : stage1;
            CVT(SW, m0, m1, 0);
            CVT(SW, m2, m3, 1);
            __syncthreads();                           // writes visible before next compute
        }
    }

    // ---- x2 (exact fp32): reduce over the 4 octets, publish ----
    x2p += __shfl_xor(x2p, 1);
    x2p += __shfl_xor(x2p, 2);
    if ((lane & 3) == 0) x2s[srow] = x2p;
    __syncthreads();   // x2s ready AND all waves done with stage buffers

    // ---- epilogue: dist -> LDS region (overlays stage); fold block dist-sum here ----
    float* region = (float*)smem;
    const int cbase = lane & 15;
    const int rbase = (lane >> 4) * 4;
    float dsum = 0.f;
#pragma unroll
    for (int i = 0; i < 2; ++i)
#pragma unroll
        for (int j = 0; j < 2; ++j) {
            const int lrt = 2 * wr + i;
            const float xj = x2s[(2 * wc + j) * 16 + cbase];
#pragma unroll
            for (int r = 0; r < 4; ++r) {
                int lrow = lrt * 16 + rbase + r;
                float xi = x2s[ib + lrow];
                float d2 = xi + xj - 2.f * acc[i][j][r];
                float dd = sqrtf(fmaxf(d2, 0.f) + 1e-12f);
                dsum += dd;
                region[lrow * PITCH + (2 * wc + j) * 16 + cbase] = dd;
            }
        }
#pragma unroll
    for (int off = 32; off >= 1; off >>= 1) dsum += __shfl_xor(dsum, off);
    if (lane == 0) wred[16 + w] = dsum;
    __syncthreads();

    // ---- mining: wave-private (wave w owns local anchors w*4..w*4+3) ----
    const unsigned long long lmask = (1ull << lane) - 1ull;
    float hardAcc = 0.f;

    for (int a = 0; a < 4; ++a) {
        const int ii = w * 4 + a;
        const int li = lli[a];                    // wave-uniform (hoisted)

        // issue all 4 dist-chunk reads upfront (pipelined)
        float dch[4];
#pragma unroll
        for (int ch = 0; ch < 4; ++ch)
            dch[ch] = region[ii * PITCH + ch * 64 + lane];

        int runMatch = 0;
        float negmin = 3.4e38f;
        int nqv[4]; int nval[4];
#pragma unroll
        for (int ch = 0; ch < 4; ++ch) {
            const int j = ch * 64 + lane;
            bool match = (llab[ch] == li);
            unsigned long long bal = __ballot(match);
            int posRank = runMatch + __popcll(bal & lmask);
            if (match) {
                if (posRank < NPOS) posbuf[w][posRank] = dch[ch];
                nval[ch] = 0; nqv[ch] = 0;
            } else {
                nqv[ch] = j - posRank; nval[ch] = 1;
                negmin = fminf(negmin, dch[ch]);
            }
            runMatch += __popcll(bal);
        }
        asm volatile("s_waitcnt lgkmcnt(0)" ::: "memory");  // same-wave posbuf drain

        // read the 8 positives ONCE into registers (manual CSE for the hinge loop)
        float pd[NPOS];
#pragma unroll
        for (int pp = 0; pp < NPOS; ++pp) pd[pp] = posbuf[w][pp];

        float maxpos = pd[0];
#pragma unroll
        for (int pp = 1; pp < NPOS; ++pp) maxpos = fmaxf(maxpos, pd[pp]);
#pragma unroll
        for (int off = 32; off >= 1; off >>= 1)
            negmin = fminf(negmin, __shfl_xor(negmin, off));
        hardAcc += fmaxf(MARG + maxpos - negmin, 0.f);

#pragma unroll
        for (int ch = 0; ch < 4; ++ch) {
            if (nval[ch]) {
                float dneg = dch[ch]; int q = nqv[ch];
                float s = 0.f, cnt = 0.f;
#pragma unroll
                for (int pp = 0; pp < NPOS; ++pp) {
                    float v = MARG + pd[pp] - dneg;
                    s   += fmaxf(v, 0.f);
                    cnt += (v > 0.f) ? 1.f : 0.f;
                }
                fullS[w][q] += s;   // per-wave private; q distinct per lane
                fullC[w][q] += cnt;
            }
        }
    }

    if (lane == 0) wred[w] = hardAcc;
    __syncthreads();

    float* rec = recs + (size_t)swz * REC;
    if (t < NNEG) {
        float s = 0.f, c = 0.f;
#pragma unroll
        for (int v = 0; v < 16; ++v) { s += fullS[v][t]; c += fullC[v][t]; }
        rec[t] = s;
        rec[NNEG + t] = c;
    }
    if (t == 0) {
        float h = 0.f, ds = 0.f;
#pragma unroll
        for (int v = 0; v < 16; ++v) { h += wred[v]; ds += wred[16 + v]; }
        rec[496] = h;
        rec[497] = ds;
    }
}

// ======================= merged finalize: 63 blocks, 4 recs/part =======================
__global__ __launch_bounds__(256) void k_fin(const float* __restrict__ recs,
                                             float* __restrict__ out)
{
    const int p = blockIdx.x;
    const int t = threadIdx.x;
    if (p < NPART) {
        if (t < NNEG) {
            float s = 0.f, c = 0.f;
#pragma unroll
            for (int a = 0; a < 4; ++a) {
                const float* rec = recs + (size_t)(p * 4 + a) * REC;
                s += rec[t];
                c += rec[NNEG + t];
            }
            out[p * NNEG + t]          = s / (c + 1e-6f);
            out[OFF_FN + p * NNEG + t] = c;
        }
        if (t == 0) {
            float h = 0.f;
#pragma unroll
            for (int a = 0; a < 4; ++a) h += recs[(size_t)(p * 4 + a) * REC + 496];
            out[OFF_HARD + p] = h * (1.0f / 256.0f);
        }
    } else {
        __shared__ float red[4];
        float v = (t < 248) ? recs[(size_t)t * REC + 497] : 0.f;
#pragma unroll
        for (int off = 32; off >= 1; off >>= 1) v += __shfl_xor(v, off);
        if ((t & 63) == 0) red[t >> 6] = v;
        __syncthreads();
        if (t == 0)
            out[OFF_MD] = (red[0] + red[1] + red[2] + red[3]) / (float)((size_t)NPART * M * M);
    }
}

// ======================= fallback: proven round-1 fused path =======================
__global__ __launch_bounds__(256) void fb_main(
    const float* __restrict__ F, const int* __restrict__ label, float* __restrict__ ws)
{
    __shared__ __align__(16) float region[256 * 36];
    __shared__ float x2s[M];
    __shared__ int   lab[M];
    __shared__ float posbuf[4][NPOS];
    __shared__ float fullS[4][NNEG];
    __shared__ float fullC[4][NNEG];
    __shared__ float wred[8];

    const int bx = blockIdx.x;
    const int p  = bx >> 3;
    const int ib = (bx & 7) * 32;
    const int t  = threadIdx.x;

    lab[t] = label[p * M + t];
    for (int idx = t; idx < 4 * NNEG; idx += 256) {
        (&fullS[0][0])[idx] = 0.f;
        (&fullC[0][0])[idx] = 0.f;
    }
    __syncthreads();

    const float4* Fv = (const float4*)(F + (size_t)p * (M * DD));

    float acc[4][8];
#pragma unroll
    for (int r = 0; r < 4; ++r)
#pragma unroll
        for (int c = 0; c < 8; ++c) acc[r][c] = 0.f;

    float x2loc = 0.f;
    const int tc = t & 31;
    const int tg = t >> 5;

    for (int kt = 0; kt < 8; ++kt) {
#pragma unroll
        for (int w = 0; w < 8; ++w) {
            int ch = w * 256 + t;
            int r  = ch >> 3;
            int q  = ch & 7;
            float4 v = Fv[r * 64 + kt * 8 + q];
            float* dst = &region[r * 36 + q * 4];
            dst[0] = v.x; dst[1] = v.y; dst[2] = v.z; dst[3] = v.w;
        }
        __syncthreads();
#pragma unroll
        for (int k4 = 0; k4 < 8; ++k4) {
            float4 b = *(const float4*)&region[t * 36 + k4 * 4];
            x2loc += b.x * b.x + b.y * b.y + b.z * b.z + b.w * b.w;
        }
#pragma unroll
        for (int k4 = 0; k4 < 8; ++k4) {
            float4 a4[4], b4[8];
#pragma unroll
            for (int r = 0; r < 4; ++r)
                a4[r] = *(const float4*)&region[(ib + tg * 4 + r) * 36 + k4 * 4];
#pragma unroll
            for (int c = 0; c < 8; ++c)
                b4[c] = *(const float4*)&region[(tc + 32 * c) * 36 + k4 * 4];
#pragma unroll
            for (int r = 0; r < 4; ++r)
#pragma unroll
                for (int c = 0; c < 8; ++c)
                    acc[r][c] += a4[r].x * b4[c].x + a4[r].y * b4[c].y +
                                 a4[r].z * b4[c].z + a4[r].w * b4[c].w;
        }
        __syncthreads();
    }

    x2s[t] = x2loc;
    __syncthreads();

#pragma unroll
    for (int r = 0; r < 4; ++r) {
        int ii = tg * 4 + r;
        float xi = x2s[ib + ii];
#pragma unroll
        for (int c = 0; c < 8; ++c) {
            int j = tc + 32 * c;
            float d2 = xi + x2s[j] - 2.f * acc[r][c];
            region[ii * M + j] = sqrtf(fmaxf(d2, 0.f) + 1e-12f);
        }
    }
    __syncthreads();

    const int lane = t & 63;
    const int w    = t >> 6;
    const unsigned long long lmask = (1ull << lane) - 1ull;

    float hardAcc = 0.f;
    float rowSum  = 0.f;

    for (int a = 0; a < 8; ++a) {
        int ii = w * 8 + a;
        int li = lab[ib + ii];
        int runMatch = 0;
        float negmin = 3.4e38f;
        float ndv[4]; int nqv[4]; int nval[4];
#pragma unroll
        for (int ch = 0; ch < 4; ++ch) {
            int j = ch * 64 + lane;
            float d = region[ii * M + j];
            bool match = (lab[j] == li);
            unsigned long long bal = __ballot(match);
            int prefix  = __popcll(bal & lmask);
            int posRank = runMatch + prefix;
            if (match) {
                if (posRank < NPOS) posbuf[w][posRank] = d;
                nval[ch] = 0; ndv[ch] = 0.f; nqv[ch] = 0;
            } else {
                ndv[ch] = d; nqv[ch] = j - posRank; nval[ch] = 1;
                negmin = fminf(negmin, d);
            }
            runMatch += __popcll(bal);
            rowSum += d;
        }
        __syncthreads();

        float maxpos = posbuf[w][0];
#pragma unroll
        for (int pp = 1; pp < NPOS; ++pp) maxpos = fmaxf(maxpos, posbuf[w][pp]);
#pragma unroll
        for (int off = 32; off >= 1; off >>= 1)
            negmin = fminf(negmin, __shfl_xor(negmin, off));
        hardAcc += fmaxf(MARG + maxpos - negmin, 0.f);

#pragma unroll
        for (int ch = 0; ch < 4; ++ch) {
            if (nval[ch]) {
                float dneg = ndv[ch]; int q = nqv[ch];
                float s = 0.f, cnt = 0.f;
#pragma unroll
                for (int pp = 0; pp < NPOS; ++pp) {
                    float v = MARG + posbuf[w][pp] - dneg;
                    if (v > 0.f) { s += v; cnt += 1.f; }
                }
                fullS[w][q] += s;
                fullC[w][q] += cnt;
            }
        }
        __syncthreads();
    }

#pragma unroll
    for (int off = 32; off >= 1; off >>= 1) rowSum += __shfl_xor(rowSum, off);
    if (lane == 0) { wred[w] = hardAcc; wred[4 + w] = rowSum; }
    __syncthreads();

    float* rec = ws + (size_t)bx * REC;
    if (t < NNEG) {
        float s = fullS[0][t] + fullS[1][t] + fullS[2][t] + fullS[3][t];
        float c = fullC[0][t] + fullC[1][t] + fullC[2][t] + fullC[3][t];
        rec[t] = s;
        rec[NNEG + t] = c;
    }
    if (t == 0) {
        rec[496] = wred[0] + wred[1] + wred[2] + wred[3];
        rec[497] = wred[4] + wred[5] + wred[6] + wred[7];
    }
}

__global__ __launch_bounds__(256) void fb_fin(const float* __restrict__ recs,
                                              float* __restrict__ out)
{
    const int p = blockIdx.x;
    const int t = threadIdx.x;
    if (p < NPART) {
        if (t < NNEG) {
            float s = 0.f, c = 0.f;
            for (int a = 0; a < 8; ++a) {
                const float* rec = recs + (size_t)(p * 8 + a) * REC;
                s += rec[t];
                c += rec[NNEG + t];
            }
            out[p * NNEG + t]          = s / (c + 1e-6f);
            out[OFF_FN + p * NNEG + t] = c;
        }
        if (t == 0) {
            float h = 0.f;
            for (int a = 0; a < 8; ++a) h += recs[(size_t)(p * 8 + a) * REC + 496];
            out[OFF_HARD + p] = h * (1.0f / 256.0f);
        }
    } else {
        __shared__ float red[4];
        float v = 0.f;
        for (int i = t; i < 496; i += 256) v += recs[(size_t)i * REC + 497];
#pragma unroll
        for (int off = 32; off >= 1; off >>= 1) v += __shfl_xor(v, off);
        if ((t & 63) == 0) red[t >> 6] = v;
        __syncthreads();
        if (t == 0)
            out[OFF_MD] = (red[0] + red[1] + red[2] + red[3]) / (float)((size_t)NPART * M * M);
    }
}

// ======================= launch =======================
extern "C" void kernel_launch(void* const* d_in, const int* in_sizes, int n_in,
                              void* d_out, int out_size, void* d_ws, size_t ws_size,
                              hipStream_t stream)
{
    const float* F     = (const float*)d_in[0];
    const int*   label = (const int*)d_in[1];
    float*       ws    = (float*)d_ws;
    float*       out   = (float*)d_out;

    if (ws_size >= WS_NEED) {
        k_all<<<dim3(248), dim3(1024), 0, stream>>>(F, label, ws);
        k_fin<<<dim3(63),  dim3(256),  0, stream>>>(ws, out);
    } else {
        fb_main<<<dim3(496), dim3(256), 0, stream>>>(F, label, ws);
        fb_fin <<<dim3(63),  dim3(256), 0, stream>>>(ws, out);
    }
}